// Round 1
// baseline (426.348 us; speedup 1.0000x reference)
//
#include <hip/hip_runtime.h>
#include <hip/hip_bf16.h>

// y_i = x_i^T Q x_i + b^T x_i + c ; N=16384, D=1024, fp32.
// Trick: x^T Q x == x^T Q^T x, so use B = Q^T -> B-fragments read contiguous
// rows of Q (coalesced staging). Fuse the final dot: per column tile,
// acc += (C + b[n]) * x[row][n]; sum over tiles + shuffle-reduce.

#define DD 1024
#define KSTEPS 32        // K / 32
#define NT 64            // D / 16 column tiles
#define LDS_STRIDE 1032  // bf16 elems per staged row (+8 pad -> 2-way only)

typedef short v8s __attribute__((ext_vector_type(8)));
typedef float v4f __attribute__((ext_vector_type(4)));

__device__ __forceinline__ short f2b(float f) {
    union { __hip_bfloat16 h; short s; } u;
    u.h = __float2bfloat16(f);
    return u.s;
}

__global__ __launch_bounds__(256, 2)
void quad_kernel(const float* __restrict__ x, const float* __restrict__ Q,
                 const float* __restrict__ bvec, const float* __restrict__ cptr,
                 float* __restrict__ y)
{
    __shared__ short lq[16 * LDS_STRIDE];  // Q^T tile: [nn][k] bf16

    const int tid  = threadIdx.x;
    const int lane = tid & 63;
    const int wave = tid >> 6;
    const int quad = lane >> 4;
    const int l15  = lane & 15;

    const int row_base = blockIdx.x * 64 + wave * 16;

    // ---- Phase 1: this wave's 16 rows of x, full K, as A-frags in regs ----
    // A layout (16x16x32): m = lane&15, k = quad*8 + j  (8 contiguous bf16)
    v8s afrag[KSTEPS];
    {
        const float* xr = x + (size_t)(row_base + l15) * DD + quad * 8;
        #pragma unroll
        for (int kt = 0; kt < KSTEPS; ++kt) {
            const float4 f0 = *(const float4*)(xr + kt * 32);
            const float4 f1 = *(const float4*)(xr + kt * 32 + 4);
            v8s a;
            a[0] = f2b(f0.x); a[1] = f2b(f0.y); a[2] = f2b(f0.z); a[3] = f2b(f0.w);
            a[4] = f2b(f1.x); a[5] = f2b(f1.y); a[6] = f2b(f1.z); a[7] = f2b(f1.w);
            afrag[kt] = a;
        }
    }

    float acc[4] = {0.f, 0.f, 0.f, 0.f};

    for (int t = 0; t < NT; ++t) {
        __syncthreads();  // protect LDS from previous tile's readers

        // ---- Stage Q^T tile: Q rows [16t, 16t+16), all K, fp32 -> bf16 ----
        {
            const float* qb = Q + (size_t)(t * 16) * DD;
            #pragma unroll
            for (int i = 0; i < 16; ++i) {
                const int idx = tid + i * 256;   // float4 index in [0,4096)
                const int nn  = idx >> 8;        // staged row 0..15
                const int k4  = idx & 255;       // float4 within row
                const float4 f = *(const float4*)(qb + (size_t)nn * DD + k4 * 4);
                short4 s;
                s.x = f2b(f.x); s.y = f2b(f.y); s.z = f2b(f.z); s.w = f2b(f.w);
                *(short4*)(&lq[nn * LDS_STRIDE + k4 * 4]) = s;
            }
        }
        __syncthreads();

        // ---- K loop: C[16x16] = A(16xK) * B(Kx16), B[k][n] = Q[16t+n][k] ----
        v4f cf = {0.f, 0.f, 0.f, 0.f};
        const short* bp = &lq[l15 * LDS_STRIDE + quad * 8];
        #pragma unroll
        for (int kt = 0; kt < KSTEPS; ++kt) {
            const v8s bfrag = *(const v8s*)(bp + kt * 32);
            cf = __builtin_amdgcn_mfma_f32_16x16x32_bf16(afrag[kt], bfrag, cf, 0, 0, 0);
        }

        // ---- Fused dot: C layout col = lane&15, row = quad*4 + reg ----
        const int n = t * 16 + l15;
        const float bn = bvec[n];
        const float* xc = x + (size_t)(row_base + quad * 4) * DD + n;
        #pragma unroll
        for (int r = 0; r < 4; ++r) {
            const float xv = xc[(size_t)r * DD];
            acc[r] += (cf[r] + bn) * xv;
        }
    }

    // ---- Reduce across the 16 lanes of each quad, write 4 rows/quad ----
    const float cc = cptr[0];
    #pragma unroll
    for (int r = 0; r < 4; ++r) {
        float v = acc[r];
        v += __shfl_xor(v, 1);
        v += __shfl_xor(v, 2);
        v += __shfl_xor(v, 4);
        v += __shfl_xor(v, 8);
        if (l15 == 0) y[row_base + quad * 4 + r] = v + cc;
    }
}

extern "C" void kernel_launch(void* const* d_in, const int* in_sizes, int n_in,
                              void* d_out, int out_size, void* d_ws, size_t ws_size,
                              hipStream_t stream)
{
    const float* x = (const float*)d_in[0];
    const float* Q = (const float*)d_in[1];
    const float* b = (const float*)d_in[2];
    const float* c = (const float*)d_in[3];
    float* y = (float*)d_out;

    quad_kernel<<<dim3(256), dim3(256), 0, stream>>>(x, Q, b, c, y);
}

// Round 2
// 164.649 us; speedup vs baseline: 2.5894x; 2.5894x over previous
//
#include <hip/hip_runtime.h>
#include <hip/hip_bf16.h>

// y_i = x_i^T Q x_i + b^T x_i + c ; N=16384, D=1024, fp32.
// Design: x^T Q x == x^T Q^T x, so B = Q^T -> B-frags come from contiguous
// Q rows. Each wave owns 16 rows of x, FULL K, as A-frags pinned in AGPRs
// (asm "+a": round 1 showed the compiler spills them from VGPRs -> 352us).
// Block = 8 waves = 128 rows; split-D by 2 (half the column tiles per block)
// -> grid 256, 8 waves/CU. Q tiles staged fp32->bf16 through double-buffered
// LDS in 16x512 chunks, one barrier per chunk, global prefetch in flight
// across the MFMA phase. Fused epilogue: acc += (C + b[n]) * x[row][n],
// 16-lane shuffle reduce, atomicAdd into y (memset to 0 on stream first).

#define DD 1024
#define KSTEPS 32        // K/32 MFMA steps total
#define NTILE 32         // column tiles per D-half
#define LDS_ROW 520      // 512 + 8 pad (shorts) -> benign 2-way bank aliasing

typedef short v8s __attribute__((ext_vector_type(8)));
typedef float v4f __attribute__((ext_vector_type(4)));

__device__ __forceinline__ short f2b(float f) {
    union { __hip_bfloat16 h; short s; } u;
    u.h = __float2bfloat16(f);
    return u.s;
}

__global__ __launch_bounds__(512, 2)
void quad_kernel(const float* __restrict__ x, const float* __restrict__ Q,
                 const float* __restrict__ bvec, const float* __restrict__ cptr,
                 float* __restrict__ y)
{
    __shared__ short lq[2][16 * LDS_ROW];   // 2 x 16.6 KB staging buffers

    const int tid  = threadIdx.x;
    const int lane = tid & 63;
    const int wave = tid >> 6;
    const int quad = lane >> 4;
    const int l15  = lane & 15;

    const int half = blockIdx.x >> 7;       // which 32-tile D-half
    const int rblk = blockIdx.x & 127;
    const int row_base = rblk * 128 + wave * 16;
    const int t0 = half * NTILE;

    const float cc = (half == 0) ? cptr[0] : 0.f;

    // ---- Phase 1: 16 rows x full K of x as bf16 A-frags, pinned in AGPRs ----
    // A layout (16x16x32): m = lane&15, k = quad*8 + j (8 contiguous bf16)
    v8s afrag[KSTEPS];
    {
        const float* xr = x + (size_t)(row_base + l15) * DD + quad * 8;
        #pragma unroll
        for (int kt = 0; kt < KSTEPS; ++kt) {
            const float4 f0 = *(const float4*)(xr + kt * 32);
            const float4 f1 = *(const float4*)(xr + kt * 32 + 4);
            v8s a;
            a[0]=f2b(f0.x); a[1]=f2b(f0.y); a[2]=f2b(f0.z); a[3]=f2b(f0.w);
            a[4]=f2b(f1.x); a[5]=f2b(f1.y); a[6]=f2b(f1.z); a[7]=f2b(f1.w);
            afrag[kt] = a;
            asm volatile("" : "+a"(afrag[kt]));   // force AGPR residency
        }
    }

    // ---- Staging map: chunk = 16 rows x 512 floats = 2048 float4 / 512 thr ----
    int s_nn[4], s_k4[4];
    #pragma unroll
    for (int i = 0; i < 4; ++i) {
        const int idx = tid + i * 512;
        s_nn[i] = idx >> 7;
        s_k4[i] = idx & 127;
    }

    // prefetch chunk 0 (tile t0, k [0,512))
    float4 pf[4];
    #pragma unroll
    for (int i = 0; i < 4; ++i)
        pf[i] = *(const float4*)(Q + (size_t)(t0 * 16 + s_nn[i]) * DD + s_k4[i] * 4);

    float acc[4] = {0.f, 0.f, 0.f, 0.f};
    v4f cf = {0.f, 0.f, 0.f, 0.f};
    float xv[4], bn;

    const short* bp0 = &lq[0][l15 * LDS_ROW + quad * 8];
    const short* bp1 = &lq[1][l15 * LDS_ROW + quad * 8];

    for (int t = 0; t < NTILE; ++t) {
        const int tg = t0 + t;                 // global tile (16 Q rows)

        // ===== PHASE A: chunk 2t -> buf 0, MFMA steps 0..15 =====
        #pragma unroll
        for (int i = 0; i < 4; ++i) {
            const float4 f = pf[i];
            short4 s;
            s.x=f2b(f.x); s.y=f2b(f.y); s.z=f2b(f.z); s.w=f2b(f.w);
            *(short4*)&lq[0][s_nn[i] * LDS_ROW + s_k4[i] * 4] = s;
        }
        // prefetch chunk 2t+1 (same tile, k [512,1024))
        #pragma unroll
        for (int i = 0; i < 4; ++i)
            pf[i] = *(const float4*)(Q + (size_t)(tg * 16 + s_nn[i]) * DD + 512 + s_k4[i] * 4);
        // prefetch fused-dot operands for this tile (consumed end of phase B)
        {
            const int n = tg * 16 + l15;
            bn = bvec[n];
            const float* xc = x + (size_t)(row_base + quad * 4) * DD + n;
            #pragma unroll
            for (int r = 0; r < 4; ++r) xv[r] = xc[(size_t)r * DD];
        }
        __syncthreads();
        #pragma unroll
        for (int s = 0; s < 16; ++s) {
            const v8s bfrag = *(const v8s*)(bp0 + s * 32);
            cf = __builtin_amdgcn_mfma_f32_16x16x32_bf16(afrag[s], bfrag, cf, 0, 0, 0);
        }

        // ===== PHASE B: chunk 2t+1 -> buf 1, MFMA steps 16..31 =====
        #pragma unroll
        for (int i = 0; i < 4; ++i) {
            const float4 f = pf[i];
            short4 s;
            s.x=f2b(f.x); s.y=f2b(f.y); s.z=f2b(f.z); s.w=f2b(f.w);
            *(short4*)&lq[1][s_nn[i] * LDS_ROW + s_k4[i] * 4] = s;
        }
        if (t + 1 < NTILE) {   // prefetch chunk 2t+2 (next tile, k [0,512))
            #pragma unroll
            for (int i = 0; i < 4; ++i)
                pf[i] = *(const float4*)(Q + (size_t)((tg + 1) * 16 + s_nn[i]) * DD + s_k4[i] * 4);
        }
        __syncthreads();
        #pragma unroll
        for (int s = 0; s < 16; ++s) {
            const v8s bfrag = *(const v8s*)(bp1 + s * 32);
            cf = __builtin_amdgcn_mfma_f32_16x16x32_bf16(afrag[16 + s], bfrag, cf, 0, 0, 0);
        }

        // ---- fused dot: C layout col = lane&15, row = quad*4 + reg ----
        #pragma unroll
        for (int r = 0; r < 4; ++r) acc[r] += (cf[r] + bn) * xv[r];
        cf = (v4f){0.f, 0.f, 0.f, 0.f};
    }

    // ---- reduce across the 16 lanes of each quad, atomic into y ----
    #pragma unroll
    for (int r = 0; r < 4; ++r) {
        float v = acc[r];
        v += __shfl_xor(v, 1);
        v += __shfl_xor(v, 2);
        v += __shfl_xor(v, 4);
        v += __shfl_xor(v, 8);
        if (l15 == 0) atomicAdd(&y[row_base + quad * 4 + r], v + cc);
    }
}

extern "C" void kernel_launch(void* const* d_in, const int* in_sizes, int n_in,
                              void* d_out, int out_size, void* d_ws, size_t ws_size,
                              hipStream_t stream)
{
    const float* x = (const float*)d_in[0];
    const float* Q = (const float*)d_in[1];
    const float* b = (const float*)d_in[2];
    const float* c = (const float*)d_in[3];
    float* y = (float*)d_out;

    hipMemsetAsync(y, 0, (size_t)out_size * sizeof(float), stream);
    quad_kernel<<<dim3(256), dim3(512), 0, stream>>>(x, Q, b, c, y);
}